// Round 1
// 851.786 us; speedup vs baseline: 1.2025x; 1.2025x over previous
//
#include <hip/hip_runtime.h>
#include <stdint.h>

typedef float  f4     __attribute__((ext_vector_type(4)));
typedef float  f32x4  __attribute__((ext_vector_type(4)));
typedef __bf16 bf16x8 __attribute__((ext_vector_type(8)));

#define AS_GLOBAL __attribute__((address_space(1)))
#define AS_LDS    __attribute__((address_space(3)))

constexpr int Bdim = 4, T = 256, U = 128, E = 512, Dd = 640, J = 640, V = 1024;

// async global->LDS, 16B per lane. LDS dest = wave-uniform base + lane*16 (linear!),
// so any swizzle must be applied on the GLOBAL source address (rule 21).
__device__ __forceinline__ void lds_load16(void* lds, const void* g) {
  __builtin_amdgcn_global_load_lds(
      (const AS_GLOBAL uint32_t*)(uintptr_t)g,
      (AS_LDS uint32_t*)(uint32_t)(uintptr_t)lds, 16, 0, 0);
}

__device__ __forceinline__ float fast_tanh(float x) {
  // tanh(x) = 1 - 2/(1+e^{2x}); exp2/rcp HW approx, err ~1e-6 (bf16 output anyway)
  float e = __builtin_amdgcn_exp2f(x * 2.88539008177f);  // 2*log2(e)
  return 1.0f - 2.0f * __builtin_amdgcn_rcpf(e + 1.0f);
}

// ---------------- projection: out[r][j] = X[r]@W[:,j] + bias[j] ----------------
// block = 256 thr = (2 e-halves) x (128 j-slots), TM=4 rows/block, JT=5 (J=640=5*128)
__global__ __launch_bounds__(256) void proj_kernel(
    const float* __restrict__ X, const float* __restrict__ W,
    const float* __restrict__ bias, float* __restrict__ out, int K) {
  const int tid = threadIdx.x;
  const int jt  = tid & 127;
  const int h   = tid >> 7;
  const int r0  = blockIdx.x * 4;
  __shared__ float sX[4 * 640];
  __shared__ float sAcc[4 * 5 * 128];

  for (int idx = tid * 4; idx < 4 * K; idx += 1024)
    *(f4*)&sX[idx] = *(const f4*)&X[(size_t)r0 * K + idx];
  __syncthreads();

  float acc[4][5] = {};
  const int e0 = h * (K >> 1), e1 = e0 + (K >> 1);
  for (int e = e0; e < e1; e += 4) {
    f4 xr[4];
#pragma unroll
    for (int r = 0; r < 4; ++r) xr[r] = *(const f4*)&sX[r * K + e];
#pragma unroll
    for (int i = 0; i < 4; ++i) {
#pragma unroll
      for (int q = 0; q < 5; ++q) {
        float w = W[(size_t)(e + i) * J + q * 128 + jt];
#pragma unroll
        for (int r = 0; r < 4; ++r) acc[r][q] = fmaf(xr[r][i], w, acc[r][q]);
      }
    }
  }
  if (h == 1) {
#pragma unroll
    for (int r = 0; r < 4; ++r)
#pragma unroll
      for (int q = 0; q < 5; ++q) sAcc[(r * 5 + q) * 128 + jt] = acc[r][q];
  }
  __syncthreads();
  if (h == 0) {
#pragma unroll
    for (int r = 0; r < 4; ++r)
#pragma unroll
      for (int q = 0; q < 5; ++q) {
        float v = acc[r][q] + sAcc[(r * 5 + q) * 128 + jt] + bias[q * 128 + jt];
        out[(size_t)(r0 + r) * J + q * 128 + jt] = v;
      }
  }
}

// ---------------- W_joint (J,V) fp32 -> Wt (V,J) bf16 ----------------
__global__ __launch_bounds__(256) void transpose_wj(const float* __restrict__ W,
                                                    __bf16* __restrict__ Wt) {
  __shared__ float t[32][33];
  const int v0 = blockIdx.x * 32, j0 = blockIdx.y * 32;
  const int c = threadIdx.x & 31, r = threadIdx.x >> 5;  // r: 0..7
#pragma unroll
  for (int rr = 0; rr < 4; ++rr)
    t[r + rr * 8][c] = W[(size_t)(j0 + r + rr * 8) * V + v0 + c];
  __syncthreads();
#pragma unroll
  for (int rr = 0; rr < 4; ++rr)
    Wt[(size_t)(v0 + r + rr * 8) * J + j0 + c] = (__bf16)t[c][r + rr * 8];
}

// ---------------- fused joint v2 ----------------
// out[(bt*U+u)][v] = tanh(ep[bt]+dp[b,u]) @ Wt^T + bj
// BM=64 BN=256 BK=64; grid = (V/256=4, B*T*U/64=2048); 256 thr = 4 waves,
// each wave computes 64 rows x 64 cols (acc[4][4] of 16x16 frags).
// LDS tiles are [row][8 x 16B-slots], slot XOR-swizzled with (row&7):
//   - Bs staged via global_load_lds with the XOR folded into the SOURCE k-offset
//   - As written with the XOR on the ds_write address
// -> conflict-free ds_read_b128 on both operands (was 8-way at BK=32).
// tanh redundancy: V/BN = 4x (was 8x); per-block A-tile half as big.
constexpr int JBM = 64, JBN = 256, JBK = 64;

__global__ __launch_bounds__(256, 3) void joint_kernel(
    const float* __restrict__ ep, const float* __restrict__ dp,
    const __bf16* __restrict__ Wt, const float* __restrict__ bj,
    float* __restrict__ out) {
  const int mblk = blockIdx.y;
  const int bt   = mblk >> 1;           // U/BM = 2 m-blocks per (b,t)
  const int u0   = (mblk & 1) * JBM;
  const int b    = bt >> 8;             // T=256
  const int v0   = blockIdx.x * JBN;
  const int tid  = threadIdx.x;
  const int wv   = tid >> 6, lane = tid & 63;
  const int lrow = lane & 15, lq = lane >> 4;

  __shared__ __align__(16) __bf16 As[JBM * JBK];  // 8 KB, rows of 128B
  __shared__ __align__(16) __bf16 Bs[JBN * JBK];  // 32 KB, rows of 128B

  const float* epr = ep + (size_t)bt * J;
  const float* dpr = dp + ((size_t)b * U + u0) * J;

  // bias folded into accumulator init (col = lane&15 of each fragment)
  f32x4 acc[4][4];
#pragma unroll
  for (int fn = 0; fn < 4; ++fn) {
    const float bv = bj[v0 + wv * 64 + fn * 16 + lrow];
#pragma unroll
    for (int fm = 0; fm < 4; ++fm) acc[fm][fn] = (f32x4){bv, bv, bv, bv};
  }

  // A staging coords: chunk c = tid (+256): row = c>>3, source slot = c&7
  const int ar = tid >> 3;        // 0..31
  const int as = tid & 7;         // source k-slot (8 bf16 = 16B)
  const int aw = (as ^ (ar & 7)); // swizzled write slot (row&7 invariant under +32)

  for (int k0 = 0; k0 < J; k0 += JBK) {
    // --- Bs: 2048 16B chunks, linear LDS dest, XOR-swizzled global source ---
    // c = i*256+tid: n = i*32 + (tid>>3); n&7 == (tid>>3)&7 (i-independent)
    {
      const int ssrc = as ^ (ar & 7);  // source slot for this thread's chunks
      const __bf16* src0 = Wt + (size_t)(v0 + ar) * J + k0 + ssrc * 8;
#pragma unroll
      for (int i = 0; i < 8; ++i)
        lds_load16((char*)Bs + (size_t)(i * 256 + tid) * 16,
                   src0 + (size_t)i * 32 * J);
    }
    // --- As: tanh(dp+ep) -> bf16, swizzled ds_write, 2 x 8 elems/thread ---
#pragma unroll
    for (int hh = 0; hh < 2; ++hh) {
      const int r = ar + hh * 32;
      const float* ds = dpr + (size_t)r * J + k0 + as * 8;
      const float* es = epr + k0 + as * 8;
      f4 d0 = *(const f4*)ds, d1 = *(const f4*)(ds + 4);
      f4 e0 = *(const f4*)es, e1 = *(const f4*)(es + 4);
      bf16x8 av;
#pragma unroll
      for (int i = 0; i < 4; ++i) av[i]     = (__bf16)fast_tanh(d0[i] + e0[i]);
#pragma unroll
      for (int i = 0; i < 4; ++i) av[i + 4] = (__bf16)fast_tanh(d1[i] + e1[i]);
      *(bf16x8*)((char*)As + r * 128 + aw * 16) = av;
    }
    __syncthreads();  // drains vmcnt (gll) + lgkm (ds_write)

    // --- MFMA: 2 k-halves x (4+4 ds_read_b128 + 16 mfma) per wave ---
#pragma unroll
    for (int hh = 0; hh < 2; ++hh) {
      bf16x8 af[4], bfr[4];
#pragma unroll
      for (int f = 0; f < 4; ++f) {
        const int rm = f * 16 + lrow;
        af[f] = *(const bf16x8*)((char*)As + rm * 128 +
                                 (((lq + 4 * hh) ^ (rm & 7)) * 16));
        const int rn = wv * 64 + f * 16 + lrow;
        bfr[f] = *(const bf16x8*)((char*)Bs + rn * 128 +
                                  (((lq + 4 * hh) ^ (rn & 7)) * 16));
      }
#pragma unroll
      for (int fm = 0; fm < 4; ++fm)
#pragma unroll
        for (int fn = 0; fn < 4; ++fn)
          acc[fm][fn] = __builtin_amdgcn_mfma_f32_16x16x32_bf16(
              af[fm], bfr[fn], acc[fm][fn], 0, 0, 0);
    }
    __syncthreads();
  }

  // epilogue: C/D layout col=lane&15, row=(lane>>4)*4+i  [m89]
  const size_t rowbase = (size_t)bt * U + u0;
#pragma unroll
  for (int fn = 0; fn < 4; ++fn) {
    const int col = v0 + wv * 64 + fn * 16 + lrow;
#pragma unroll
    for (int fm = 0; fm < 4; ++fm) {
      const int u = fm * 16 + lq * 4;
#pragma unroll
      for (int i = 0; i < 4; ++i)
        out[(rowbase + u + i) * (size_t)V + col] = acc[fm][fn][i];
    }
  }
}

extern "C" void kernel_launch(void* const* d_in, const int* in_sizes, int n_in,
                              void* d_out, int out_size, void* d_ws, size_t ws_size,
                              hipStream_t stream) {
  (void)in_sizes; (void)n_in; (void)out_size; (void)ws_size;
  const float* enc    = (const float*)d_in[0];
  const float* dec    = (const float*)d_in[1];
  const float* W_enc  = (const float*)d_in[2];
  const float* b_enc  = (const float*)d_in[3];
  const float* W_dec  = (const float*)d_in[4];
  const float* b_dec  = (const float*)d_in[5];
  const float* W_jnt  = (const float*)d_in[6];
  const float* b_jnt  = (const float*)d_in[7];
  float* out = (float*)d_out;

  // workspace: ep (1024x640 f32) | dp (512x640 f32) | Wt (1024x640 bf16)  ~5.24 MB
  float*  ep = (float*)d_ws;
  float*  dp = ep + (size_t)Bdim * T * J;
  __bf16* Wt = (__bf16*)(dp + (size_t)Bdim * U * J);

  proj_kernel<<<dim3(Bdim * T / 4), 256, 0, stream>>>(enc, W_enc, b_enc, ep, E);
  proj_kernel<<<dim3(Bdim * U / 4), 256, 0, stream>>>(dec, W_dec, b_dec, dp, Dd);
  transpose_wj<<<dim3(V / 32, J / 32), 256, 0, stream>>>(W_jnt, Wt);
  joint_kernel<<<dim3(V / JBN, Bdim * T * U / JBM), 256, 0, stream>>>(ep, dp, Wt, b_jnt, out);
}